// Round 2
// baseline (2225.719 us; speedup 1.0000x reference)
//
#include <hip/hip_runtime.h>

#define HO 62
#define WO 62
#define CIN 32
#define COUT 64
#define BATCH 16
#define KROW 288          // CIN*9, contiguous k per (position,o)
#define JT 2              // j positions per block
#define COLS 4            // JT+2 window columns
#define NCHUNK 8          // K chunks (4 c's each)
#define CF 36             // floats per o-row per chunk
#define WROW 37           // padded LDS row (37%32=5 -> bank rotation, 2 lanes/bank)
#define POSW (COUT * WROW)

__device__ __forceinline__ float sigmoidf(float v) {
    return 1.0f / (1.0f + __expf(-v));
}

__global__ __launch_bounds__(256, 2)
void lc2d_kernel(const float* __restrict__ x,
                 const float* __restrict__ wgt,
                 float* __restrict__ out) {
    __shared__ __align__(16) float win[CIN][3][COLS][BATCH];   // 24576 B
    __shared__ __align__(16) float wlds[2][JT][POSW];          // 37888 B  (total 62464 B -> 2 blocks/CU)

    const int blk = blockIdx.x;
    const int i  = blk % HO;
    const int j0 = (blk / HO) * JT;      // 31 tiles cover 62 exactly, no tail
    const int t  = threadIdx.x;

    // ---------------- stage x window: [c][kh][col][b] ----------------
    for (int r = t; r < BATCH * CIN * 3; r += 256) {
        const int b   = r & 15;
        const int ckh = r >> 4;
        const int c   = ckh / 3;
        const int kh  = ckh - c * 3;
        const float* src = x + (((b * CIN + c) * 64) + (i + kh)) * 64 + j0;
        #pragma unroll
        for (int cc = 0; cc < COLS; cc++)
            win[c][kh][cc][b] = src[cc];
    }

    // ---------------- weight chunk staging setup ----------------
    // Per chunk: JT*64 rows * 9 float4 = 1152 float4; thread t covers f = t + 256*q.
    // f -> pos = f/576, o = (f%576)/9, kk4 = f%9.
    // Global float offset: pos*COUT*KROW + o*KROW + kk4*4 (+ ch*CF), 16B aligned.
    // Consecutive lanes walk 144B-contiguous strips -> semi-coalesced stream.
    const int nq = (t < 128) ? 5 : 4;    // 1152 = 4*256 + 128
    int goff[5], loff[5];
    #pragma unroll
    for (int q = 0; q < 5; q++) {
        int f = t + 256 * q;
        if (f >= 1152) f = 1151;         // inactive lanes: harmless dup (guarded by nq)
        const int pos = f / 576;
        const int rem = f - pos * 576;
        const int o   = rem / 9;
        const int kk4 = rem - o * 9;
        goff[q] = pos * (COUT * KROW) + o * KROW + kk4 * 4;
        loff[q] = pos * POSW + o * WROW + kk4 * 4;
    }
    const float* wslab = wgt + (size_t)(i * WO + j0) * (COUT * KROW);

    float4 st[5];

    // prologue: load + write chunk 0 into buf 0 (overlaps x staging latency)
    #pragma unroll
    for (int q = 0; q < 5; q++)
        if (q < nq) st[q] = *(const float4*)(wslab + goff[q]);
    #pragma unroll
    for (int q = 0; q < 5; q++)
        if (q < nq) {
            float* d = &wlds[0][0][0] + loff[q];
            d[0] = st[q].x; d[1] = st[q].y; d[2] = st[q].z; d[3] = st[q].w;
        }
    __syncthreads();   // x window + chunk 0 ready

    const int wsel = t >> 6;             // wave = batch quad
    const int o    = t & 63;             // lane = output channel
    const int bq4  = wsel * 4;

    float acc0[4] = {0.f, 0.f, 0.f, 0.f};
    float acc1[4] = {0.f, 0.f, 0.f, 0.f};

    #pragma unroll
    for (int ch = 0; ch < NCHUNK; ch++) {
        const int cur = ch & 1;

        // issue prefetch of chunk ch+1 (in flight across the compute below)
        if (ch + 1 < NCHUNK) {
            #pragma unroll
            for (int q = 0; q < 5; q++)
                if (q < nq) st[q] = *(const float4*)(wslab + goff[q] + (ch + 1) * CF);
        }

        // ---- compute on buf[cur] ----
        const float* w0p = &wlds[cur][0][0] + o * WROW;
        const float* w1p = &wlds[cur][1][0] + o * WROW;
        float w0[CF], w1[CF];
        #pragma unroll
        for (int m = 0; m < CF; m++) { w0[m] = w0p[m]; w1[m] = w1p[m]; }

        const int c0 = ch * 4;
        #pragma unroll
        for (int cl = 0; cl < 4; cl++) {
            #pragma unroll
            for (int kh = 0; kh < 3; kh++) {
                const float* xb = &win[c0 + cl][kh][0][bq4];   // wave-uniform -> broadcast
                float4 xv[COLS];
                #pragma unroll
                for (int cc = 0; cc < COLS; cc++)
                    xv[cc] = *(const float4*)(xb + cc * BATCH);
                #pragma unroll
                for (int kw = 0; kw < 3; kw++) {
                    const float wa = w0[cl * 9 + kh * 3 + kw];
                    const float wb = w1[cl * 9 + kh * 3 + kw];
                    acc0[0] += wa * xv[kw].x;     acc0[1] += wa * xv[kw].y;
                    acc0[2] += wa * xv[kw].z;     acc0[3] += wa * xv[kw].w;
                    acc1[0] += wb * xv[kw + 1].x; acc1[1] += wb * xv[kw + 1].y;
                    acc1[2] += wb * xv[kw + 1].z; acc1[3] += wb * xv[kw + 1].w;
                }
            }
        }

        // ---- drain prefetch into the other buffer, then barrier ----
        if (ch + 1 < NCHUNK) {
            float* base = &wlds[cur ^ 1][0][0];
            #pragma unroll
            for (int q = 0; q < 5; q++)
                if (q < nq) {
                    float* d = base + loff[q];
                    d[0] = st[q].x; d[1] = st[q].y; d[2] = st[q].z; d[3] = st[q].w;
                }
            __syncthreads();   // nothing left in flight -> compiler's vmcnt(0) is free
        }
    }

    // ---------------- epilogue: sigmoid + float2 stores ----------------
    #pragma unroll
    for (int bb = 0; bb < 4; bb++) {
        const int b = bq4 + bb;
        float* op = out + (((size_t)(b * COUT + o) * HO + i) * WO + j0);
        float2 s;
        s.x = sigmoidf(acc0[bb]);
        s.y = sigmoidf(acc1[bb]);
        *(float2*)op = s;
    }
}

extern "C" void kernel_launch(void* const* d_in, const int* in_sizes, int n_in,
                              void* d_out, int out_size, void* d_ws, size_t ws_size,
                              hipStream_t stream) {
    const float* x   = (const float*)d_in[0];
    const float* wgt = (const float*)d_in[1];
    float* out       = (float*)d_out;
    const int grid = HO * (WO / JT);   // 62 * 31 = 1922 blocks
    lc2d_kernel<<<dim3(grid), dim3(256), 0, stream>>>(x, wgt, out);
}

// Round 3
// 1041.239 us; speedup vs baseline: 2.1376x; 2.1376x over previous
//
#include <hip/hip_runtime.h>

#define HO 62
#define WO 62
#define CIN 32
#define COUT 64
#define NB 16
#define KR 288            // floats per (pos,o) weight row
#define JT 4              // j positions per block
#define NCH 8             // c-quad chunks
#define WROW 36           // LDS row floats: exact c-quad slice, 16B aligned, even bank spread

typedef float f2 __attribute__((ext_vector_type(2)));
typedef float f4 __attribute__((ext_vector_type(4)));

__global__ __launch_bounds__(256, 3)
void lc2d_kernel(const float* __restrict__ x,
                 const float* __restrict__ wgt,
                 float* __restrict__ out)
{
    __shared__ __align__(16) float wls[JT][COUT][WROW];   // 36864 B, single-buffered
    __shared__ __align__(16) float xls[4][3][6][NB];      // 4608 B  (c-quad x window)

    const int blk = blockIdx.x;
    const int i  = blk % HO;
    const int j0 = (blk / HO) * JT;     // 16 tiles; last tile has 2 dead j's
    const int t  = threadIdx.x;
    const int wv = t >> 6;              // wave = batch quad
    const int ln = t & 63;
    const int jg = ln >> 4;             // this thread's j = j0 + jg
    const int op = ln & 15;             // o = op + 16*ko, ko = 0..3

    // ---- staging roles ----
    // weights: thread t -> one (pos, o) row; 9 aligned float4 per chunk
    const int sp = t >> 6;
    const int so = t & 63;
    int pj = j0 + sp; if (pj > WO - 1) pj = WO - 1;   // dead-j dup, results discarded
    const float* wrow = wgt + ((size_t)(i * WO + pj) * COUT + so) * KR;

    // x: threads 0..191 -> one (b, cl, kh) row, 6 cols
    const int xb  = t & 15;
    const int xq  = t >> 4;             // 0..11 valid
    const int xcl = xq & 3;
    const int xkh = xq >> 2;
    int xc2 = j0 + 4; if (xc2 > 62) xc2 = 62;   // clamp: only dead lanes consume slots 4,5 then

    f4 wst[9];
    f4 xst4; f2 xst2;

    auto loadw = [&](int ch) {
        const float* p = wrow + ch * WROW;
        #pragma unroll
        for (int q = 0; q < 9; q++) wst[q] = *(const f4*)(p + 4 * q);
    };
    auto loadx = [&](int ch) {
        if (t < 192) {
            const float* p = x + (((size_t)(xb * CIN + (ch * 4 + xcl)) * 64) + (i + xkh)) * 64;
            xst4 = *(const f4*)(p + j0);
            xst2 = *(const f2*)(p + xc2);
        }
    };
    auto writew = [&]() {
        float* d = &wls[sp][so][0];
        #pragma unroll
        for (int q = 0; q < 9; q++) *(f4*)(d + 4 * q) = wst[q];
    };
    auto writex = [&]() {
        if (t < 192) {
            float* d = &xls[xcl][xkh][0][xb];
            d[0 * NB] = xst4.x; d[1 * NB] = xst4.y; d[2 * NB] = xst4.z; d[3 * NB] = xst4.w;
            d[4 * NB] = xst2.x; d[5 * NB] = xst2.y;
        }
    };

    f4 acc[4];
    #pragma unroll
    for (int ko = 0; ko < 4; ko++) acc[ko] = (f4){0.f, 0.f, 0.f, 0.f};

    loadw(0); loadx(0);
    writew(); writex();
    __syncthreads();

    for (int ch = 0; ch < NCH; ch++) {
        if (ch + 1 < NCH) { loadw(ch + 1); loadx(ch + 1); }   // prefetch into regs

        #pragma unroll
        for (int cl = 0; cl < 4; cl++) {
            // x fragments: 9 aligned b128 broadcasts (4 distinct addrs/instr)
            f4 xv[3][3];
            #pragma unroll
            for (int kh = 0; kh < 3; kh++)
                #pragma unroll
                for (int kw = 0; kw < 3; kw++)
                    xv[kh][kw] = *(const f4*)(&xls[cl][kh][jg + kw][wv * 4]);

            #pragma unroll
            for (int ko = 0; ko < 4; ko++) {
                const float* wr = &wls[jg][op + 16 * ko][0];
                float wk[9];
                // aligned mixed-width extraction of floats [9*cl, 9*cl+9)
                if (cl == 0) {
                    f4 a = *(const f4*)(wr);      f4 b = *(const f4*)(wr + 4);
                    wk[0]=a.x; wk[1]=a.y; wk[2]=a.z; wk[3]=a.w;
                    wk[4]=b.x; wk[5]=b.y; wk[6]=b.z; wk[7]=b.w;
                    wk[8]=wr[8];
                } else if (cl == 1) {
                    wk[0]=wr[9];
                    f2 a = *(const f2*)(wr + 10);
                    f4 b = *(const f4*)(wr + 12);
                    f2 c = *(const f2*)(wr + 16);
                    wk[1]=a.x; wk[2]=a.y;
                    wk[3]=b.x; wk[4]=b.y; wk[5]=b.z; wk[6]=b.w;
                    wk[7]=c.x; wk[8]=c.y;
                } else if (cl == 2) {
                    f2 a = *(const f2*)(wr + 18);
                    f4 b = *(const f4*)(wr + 20);
                    f2 c = *(const f2*)(wr + 24);
                    wk[0]=a.x; wk[1]=a.y;
                    wk[2]=b.x; wk[3]=b.y; wk[4]=b.z; wk[5]=b.w;
                    wk[6]=c.x; wk[7]=c.y;
                    wk[8]=wr[26];
                } else {
                    wk[0]=wr[27];
                    f4 a = *(const f4*)(wr + 28);  f4 b = *(const f4*)(wr + 32);
                    wk[1]=a.x; wk[2]=a.y; wk[3]=a.z; wk[4]=a.w;
                    wk[5]=b.x; wk[6]=b.y; wk[7]=b.z; wk[8]=b.w;
                }
                #pragma unroll
                for (int kh = 0; kh < 3; kh++)
                    #pragma unroll
                    for (int kw = 0; kw < 3; kw++) {
                        const float w = wk[kh * 3 + kw];
                        acc[ko].x += w * xv[kh][kw].x;
                        acc[ko].y += w * xv[kh][kw].y;
                        acc[ko].z += w * xv[kh][kw].z;
                        acc[ko].w += w * xv[kh][kw].w;
                    }
            }
        }

        if (ch + 1 < NCH) {
            __syncthreads();     // all waves done reading this chunk
            writew(); writex();  // drain prefetch regs into LDS
            __syncthreads();     // next chunk visible
        }
    }

    // ---- epilogue ----
    const int j = j0 + jg;
    if (j < WO) {
        #pragma unroll
        for (int ko = 0; ko < 4; ko++) {
            const int o = op + 16 * ko;
            #pragma unroll
            for (int bb = 0; bb < 4; bb++) {
                const int b = wv * 4 + bb;
                const float v = (bb == 0) ? acc[ko].x : (bb == 1) ? acc[ko].y
                              : (bb == 2) ? acc[ko].z : acc[ko].w;
                out[(((size_t)(b * COUT + o) * HO) + i) * WO + j] =
                    1.0f / (1.0f + __expf(-v));
            }
        }
    }
}

extern "C" void kernel_launch(void* const* d_in, const int* in_sizes, int n_in,
                              void* d_out, int out_size, void* d_ws, size_t ws_size,
                              hipStream_t stream) {
    const float* x   = (const float*)d_in[0];
    const float* wgt = (const float*)d_in[1];
    float* out       = (float*)d_out;
    const int grid = HO * ((WO + JT - 1) / JT);   // 62 * 16 = 992
    lc2d_kernel<<<dim3(grid), dim3(256), 0, stream>>>(x, wgt, out);
}